// Round 6
// baseline (254.436 us; speedup 1.0000x reference)
//
#include <hip/hip_runtime.h>

#define B_    16
#define T_    8
#define K_    64
#define COUT  128
#define CIN   128
#define H_    64
#define W_    64
#define WSZ   (COUT*CIN*5*5)        // 409600 per-k (and per-b) weight elems

typedef __bf16 bf16x8 __attribute__((ext_vector_type(8)));
typedef float  f32x4  __attribute__((ext_vector_type(4)));
typedef unsigned int u32;

static __device__ __forceinline__ unsigned short f2bf(float f) {
    unsigned int u = __builtin_bit_cast(unsigned int, f);
    unsigned int r = (u + 0x7FFFu + ((u >> 16) & 1u)) >> 16;
    return (unsigned short)r;
}

static __device__ __forceinline__ unsigned int pack2(float lo, float hi) {
    return (unsigned int)f2bf(lo) | ((unsigned int)f2bf(hi) << 16);
}

// async global->LDS, 16B per lane, dest = wave-uniform base + lane*16
static __device__ __forceinline__ void stage16(const void* g, void* l) {
    __builtin_amdgcn_global_load_lds((const __attribute__((address_space(1))) u32*)g,
                                     (__attribute__((address_space(3))) u32*)l,
                                     16, 0, 0);
}

// ---------------------------------------------------------------------------
// Fused prep kernel. Grid 1536 blocks: [0,512) lp role, [512,1536) xtrans.
// lp role CHANGE vs R0: Wb stream staged via global_load_lds into an 8-slot
// LDS ring with counted vmcnt(7) waits (T3/T4 pacing). Each wave stages its
// own 1KB segment per k and its own lanes consume it -> no intra-loop
// barriers; vmcnt is per-wave. Issue order pinned: consume(ds_read) ->
// lgkmcnt(0) -> sched_barrier -> stage(k+8). Coefs in cs2[k][b] transposed
// layout (4x ds_read_b128 per k). xtrans role: R0-exact.
// ---------------------------------------------------------------------------
__global__ __launch_bounds__(256) void prep_kernel(const float* __restrict__ Wb,
                                                   const float* __restrict__ tf,
                                                   const float* __restrict__ x,
                                                   unsigned short* __restrict__ lpF,
                                                   unsigned short* __restrict__ xT) {
    __shared__ __align__(16) char smem[36864];   // cs2 4KB | ring 8x4KB (lt aliases ring)
    int tid = threadIdx.x;

    if (blockIdx.x < 512) {
        // ---------------- lp role ----------------
        // lpF[b][tap][kc(4)][wm(2)][mt(4)][lane(64)][j(8)]  (bf16)
        float* cs2         = (float*)smem;                       // [64][16] = 4 KB
        unsigned short* lt = (unsigned short*)(smem + 4096);     // 25.6 KB, aliases ring

        int o = blockIdx.x >> 2;      // 0..127
        int s = blockIdx.x & 3;       // c chunk: c in [32s, 32s+32)

        // coef transposed: cs2[k*16 + b] = mean_t tf[b,t,k] * 0.125
        {
            int idx = tid;
#pragma unroll
            for (int r = 0; r < 4; ++r, idx += 256) {
                int k = idx >> 4, b = idx & 15;
                float sum = 0.f;
#pragma unroll
                for (int t = 0; t < T_; ++t) sum += tf[(b * T_ + t) * K_ + k];
                cs2[idx] = sum * 0.125f;
            }
        }
        __syncthreads();

        // staging geometry: wave w stages chunk bytes [1024w, 1024w+1024) of
        // slot (k&7); its own lanes consume exactly that range.
        int wv_ = tid >> 6;                 // wave 0..3
        int ln_ = tid & 63;
        int so  = 256 * wv_ + 4 * ln_;      // src float offset in 800-float chunk
        if (so >= 800) so = 0;              // wave3 lanes>=8: clamp to one shared line
        const float* gbase = Wb + o * 3200 + s * 800 + so;       // + k*WSZ per k
        char* ring = smem + 4096;
        char* mydst = ring + wv_ * 1024;                         // + slot*4096

        // prologue: stage k = 0..7 into slots 0..7 (8 outstanding per wave)
#pragma unroll
        for (int u = 0; u < 8; ++u)
            stage16(gbase + (size_t)u * WSZ, mydst + u * 4096);

        float4 acc[B_];
#pragma unroll
        for (int b = 0; b < B_; ++b) acc[b] = make_float4(0.f, 0.f, 0.f, 0.f);

        const char* myrd = ring + tid * 16;                      // consumer (tid<200)

        for (int k = 0; k < 64; ++k) {
            int slot = k & 7;
            asm volatile("s_waitcnt vmcnt(7)" ::: "memory");     // slot k's DMA done
            float4 wvv, c0, c1, c2, c3;
            if (tid < 200) {
                wvv = *(const float4*)(myrd + slot * 4096);
                const float4* cp = (const float4*)(cs2 + k * 16);
                c0 = cp[0]; c1 = cp[1]; c2 = cp[2]; c3 = cp[3];
            }
            asm volatile("s_waitcnt lgkmcnt(0)" ::: "memory");   // reads retired
            __builtin_amdgcn_sched_barrier(0);                   // pin stage after reads
            stage16(gbase + (size_t)((k + 8) & 63) * WSZ, mydst + slot * 4096);
            if (tid < 200) {
                acc[0].x  += c0.x * wvv.x; acc[0].y  += c0.x * wvv.y;
                acc[0].z  += c0.x * wvv.z; acc[0].w  += c0.x * wvv.w;
                acc[1].x  += c0.y * wvv.x; acc[1].y  += c0.y * wvv.y;
                acc[1].z  += c0.y * wvv.z; acc[1].w  += c0.y * wvv.w;
                acc[2].x  += c0.z * wvv.x; acc[2].y  += c0.z * wvv.y;
                acc[2].z  += c0.z * wvv.z; acc[2].w  += c0.z * wvv.w;
                acc[3].x  += c0.w * wvv.x; acc[3].y  += c0.w * wvv.y;
                acc[3].z  += c0.w * wvv.z; acc[3].w  += c0.w * wvv.w;
                acc[4].x  += c1.x * wvv.x; acc[4].y  += c1.x * wvv.y;
                acc[4].z  += c1.x * wvv.z; acc[4].w  += c1.x * wvv.w;
                acc[5].x  += c1.y * wvv.x; acc[5].y  += c1.y * wvv.y;
                acc[5].z  += c1.y * wvv.z; acc[5].w  += c1.y * wvv.w;
                acc[6].x  += c1.z * wvv.x; acc[6].y  += c1.z * wvv.y;
                acc[6].z  += c1.z * wvv.z; acc[6].w  += c1.z * wvv.w;
                acc[7].x  += c1.w * wvv.x; acc[7].y  += c1.w * wvv.y;
                acc[7].z  += c1.w * wvv.z; acc[7].w  += c1.w * wvv.w;
                acc[8].x  += c2.x * wvv.x; acc[8].y  += c2.x * wvv.y;
                acc[8].z  += c2.x * wvv.z; acc[8].w  += c2.x * wvv.w;
                acc[9].x  += c2.y * wvv.x; acc[9].y  += c2.y * wvv.y;
                acc[9].z  += c2.y * wvv.z; acc[9].w  += c2.y * wvv.w;
                acc[10].x += c2.z * wvv.x; acc[10].y += c2.z * wvv.y;
                acc[10].z += c2.z * wvv.z; acc[10].w += c2.z * wvv.w;
                acc[11].x += c2.w * wvv.x; acc[11].y += c2.w * wvv.y;
                acc[11].z += c2.w * wvv.z; acc[11].w += c2.w * wvv.w;
                acc[12].x += c3.x * wvv.x; acc[12].y += c3.x * wvv.y;
                acc[12].z += c3.x * wvv.z; acc[12].w += c3.x * wvv.w;
                acc[13].x += c3.y * wvv.x; acc[13].y += c3.y * wvv.y;
                acc[13].z += c3.y * wvv.z; acc[13].w += c3.y * wvv.w;
                acc[14].x += c3.z * wvv.x; acc[14].y += c3.z * wvv.y;
                acc[14].z += c3.z * wvv.z; acc[14].w += c3.z * wvv.w;
                acc[15].x += c3.w * wvv.x; acc[15].y += c3.w * wvv.y;
                acc[15].z += c3.w * wvv.z; acc[15].w += c3.w * wvv.w;
            }
        }

        asm volatile("s_waitcnt vmcnt(0)" ::: "memory");   // drain wrap-around stages
        __syncthreads();                                   // ring dead; lt region safe

        if (tid < 200) {
            unsigned int* ltw = (unsigned int*)lt;
#pragma unroll
            for (int b = 0; b < B_; ++b) {
                ltw[b * 400 + tid * 2]     = pack2(acc[b].x, acc[b].y);
                ltw[b * 400 + tid * 2 + 1] = pack2(acc[b].z, acc[b].w);
            }
        }
        __syncthreads();

        // fragment-ordered writeout: wm,mt,n16 fixed per block; quad varies
        int wm = o >> 6, mt = (o >> 4) & 3, n16 = o & 15;
        for (int it = tid; it < 1600; it += 256) {
            int b = it / 100;
            int r = it - b * 100;
            int tap = r >> 2;
            int quad = r & 3;
            unsigned short v[8];
#pragma unroll
            for (int j = 0; j < 8; ++j)
                v[j] = lt[b * 800 + (quad * 8 + j) * 25 + tap];
            size_t off = (size_t)b * 409600
                       + (size_t)((((tap * 4 + s) * 2 + wm) * 4 + mt) * 512
                                  + quad * 128 + n16 * 8);
            *(uint4*)(lpF + off) = *(const uint4*)v;
        }
    } else {
        // ---------------- xtrans role (R0-exact) ----------------
        unsigned short* ls = (unsigned short*)smem;              // 64*136*2 = 17.4 KB
        int q = blockIdx.x - 512;
        int b = q >> 6, h = q & 63;

        int w = tid & 63, cb = tid >> 6;          // cb: 4 groups of 32 c
        const float* xp = x + (((size_t)(b * CIN + cb * 32) * H_ + h) * W_) + w;
#pragma unroll
        for (int p = 0; p < 16; ++p) {
            float f0 = xp[(size_t)(2 * p) * (H_ * W_)];
            float f1 = xp[(size_t)(2 * p + 1) * (H_ * W_)];
            *(unsigned int*)&ls[w * 136 + cb * 32 + 2 * p] = pack2(f0, f1);
        }
        __syncthreads();

        unsigned short* xTb = xT + ((size_t)(b * 64 + h) * 64) * 128;
        int chunk = tid & 15, wr = tid >> 4;
#pragma unroll
        for (int pass = 0; pass < 4; ++pass) {
            int ww = pass * 16 + wr;
            uint4 v = *(const uint4*)&ls[ww * 136 + chunk * 8];
            *(uint4*)&xTb[ww * 128 + chunk * 8] = v;
        }
    }
}

// ---------------------------------------------------------------------------
// Conv as 25 shifted GEMMs, bf16 MFMA 16x16x32, fp32 accum. R5-exact.
// Wave wq owns an o-quarter (32 o) x all 128 pixels; A read once per block.
// Grid: 512 blocks, XCD-swizzled (2 batches per XCD's L2).
// ---------------------------------------------------------------------------
__global__ __launch_bounds__(256) void conv_mfma(const unsigned short* __restrict__ xT,
                                                 const unsigned short* __restrict__ lpF,
                                                 float* __restrict__ out) {
    int bid = blockIdx.x;
    int b  = (bid & 7) | (((bid >> 3) & 1) << 3);   // XCD-local batch
    int h0 = (bid >> 4) << 1;                       // row pair

    int tid  = threadIdx.x;
    int lane = tid & 63, wq = tid >> 6;       // wq: o-quarter 0..3
    int n16 = lane & 15, quad = lane >> 4;

    __shared__ __align__(16) unsigned short xs[408 * 40];   // 32640 B

    f32x4 acc[2][8];
#pragma unroll
    for (int mt = 0; mt < 2; ++mt)
#pragma unroll
        for (int nt = 0; nt < 8; ++nt) acc[mt][nt] = (f32x4){0.f, 0.f, 0.f, 0.f};

    const unsigned short* xTb = xT + (size_t)b * (64 * 64 * 128);
    const unsigned short* lpW = lpF + (size_t)b * 409600
                              + (wq >> 1) * 2048 + (wq & 1) * 1024 + lane * 8;

#define LOAD_FRAGS(A, Bf, tap) do {                                          \
    int i_ = (tap) / 5, j_ = (tap) - 5 * (i_);                               \
    const unsigned short* ap_ = lpW + (tap) * 16384 + kcB;                   \
    A[0] = *(const bf16x8*)(ap_);                                            \
    A[1] = *(const bf16x8*)(ap_ + 512);                                      \
    const unsigned short* bp_ = &xs[((i_) * 68 + n16 + j_) * 40 + quad * 8]; \
    Bf[0] = *(const bf16x8*)(bp_);                                           \
    Bf[1] = *(const bf16x8*)(bp_ + 16 * 40);                                 \
    Bf[2] = *(const bf16x8*)(bp_ + 32 * 40);                                 \
    Bf[3] = *(const bf16x8*)(bp_ + 48 * 40);                                 \
    Bf[4] = *(const bf16x8*)(bp_ + 68 * 40);                                 \
    Bf[5] = *(const bf16x8*)(bp_ + (68 + 16) * 40);                          \
    Bf[6] = *(const bf16x8*)(bp_ + (68 + 32) * 40);                          \
    Bf[7] = *(const bf16x8*)(bp_ + (68 + 48) * 40);                          \
} while (0)

#define DO_MFMA(av, bv) do {                                                 \
    _Pragma("unroll") for (int mt = 0; mt < 2; ++mt)                         \
    _Pragma("unroll") for (int nt = 0; nt < 8; ++nt)                         \
        acc[mt][nt] = __builtin_amdgcn_mfma_f32_16x16x32_bf16(               \
            (av)[mt], (bv)[nt], acc[mt][nt], 0, 0, 0);                       \
} while (0)

    for (int kc = 0; kc < 4; ++kc) {
        int kcOff = kc * 32;
        int kcB   = kc * 4096;
        __syncthreads();                       // previous chunk's readers done
        for (int sIdx = tid; sIdx < 408; sIdx += 256) {
            unsigned int su = (unsigned int)sIdx;
            int rr = su / 68u;
            int ww = su - rr * 68u;
            int gr = h0 - 2 + rr, gw = ww - 2;
            uint4* dst = (uint4*)&xs[sIdx * 40];
            if ((unsigned)gr < 64u && (unsigned)gw < 64u) {
                const uint4* src = (const uint4*)(xTb + (((size_t)gr * 64 + gw) * 128 + kcOff));
                dst[0] = src[0]; dst[1] = src[1]; dst[2] = src[2]; dst[3] = src[3];
            } else {
                uint4 z = {0u, 0u, 0u, 0u};
                dst[0] = z; dst[1] = z; dst[2] = z; dst[3] = z;
            }
        }
        __syncthreads();

        bf16x8 a0[2], b0[8], a1[2], b1[8];
        LOAD_FRAGS(a0, b0, 0);
        for (int t = 0; t < 24; t += 2) {
            LOAD_FRAGS(a1, b1, t + 1);
            DO_MFMA(a0, b0);
            LOAD_FRAGS(a0, b0, t + 2);
            DO_MFMA(a1, b1);
        }
        DO_MFMA(a0, b0);                       // tap 24
    }

    // epilogue: o = wq*32 + mt*16 + quad*4 + r; h = h0+(nt>>2); w = (nt&3)*16+n16
    float* outb = out + (size_t)b * (COUT * H_ * W_);
#pragma unroll
    for (int mt = 0; mt < 2; ++mt) {
#pragma unroll
        for (int nt = 0; nt < 8; ++nt) {
#pragma unroll
            for (int r = 0; r < 4; ++r) {
                int o = wq * 32 + mt * 16 + quad * 4 + r;
                int h = h0 + (nt >> 2);
                int w = (nt & 3) * 16 + n16;
                outb[(size_t)o * (H_ * W_) + (size_t)h * W_ + w] = acc[mt][nt][r];
            }
        }
    }
#undef LOAD_FRAGS
#undef DO_MFMA
}

// ---------------------------------------------------------------------------
extern "C" void kernel_launch(void* const* d_in, const int* in_sizes, int n_in,
                              void* d_out, int out_size, void* d_ws, size_t ws_size,
                              hipStream_t stream) {
    const float* x  = (const float*)d_in[0];   // (16,128,64,64)
    const float* tf = (const float*)d_in[1];   // (16,8,64)
    const float* Wb = (const float*)d_in[2];   // (64,128,128,5,5)
    float* out = (float*)d_out;                // (16,128,64,64) fp32

    // ws: lpF bf16 fragment-ordered 16*409600 = 13.1 MB, then xT bf16 16.8 MB
    unsigned short* lpF = (unsigned short*)d_ws;
    unsigned short* xT  = lpF + (size_t)B_ * 409600;

    prep_kernel<<<1536, 256, 0, stream>>>(Wb, tf, x, lpF, xT);
    conv_mfma  <<<512,  256, 0, stream>>>(xT, lpF, out);
}

// Round 8
// 252.630 us; speedup vs baseline: 1.0071x; 1.0071x over previous
//
#include <hip/hip_runtime.h>

#define B_    16
#define T_    8
#define K_    64
#define COUT  128
#define CIN   128
#define H_    64
#define W_    64
#define WSZ   (COUT*CIN*5*5)        // 409600 per-k (and per-b) weight elems

typedef __bf16 bf16x8 __attribute__((ext_vector_type(8)));
typedef float  f32x4  __attribute__((ext_vector_type(4)));
typedef unsigned int u32;

static __device__ __forceinline__ unsigned short f2bf(float f) {
    unsigned int u = __builtin_bit_cast(unsigned int, f);
    unsigned int r = (u + 0x7FFFu + ((u >> 16) & 1u)) >> 16;
    return (unsigned short)r;
}

static __device__ __forceinline__ unsigned int pack2(float lo, float hi) {
    return (unsigned int)f2bf(lo) | ((unsigned int)f2bf(hi) << 16);
}

// async global->LDS, 16B per lane, dest = wave-uniform base + lane*16
static __device__ __forceinline__ void stage16(const void* g, void* l) {
    __builtin_amdgcn_global_load_lds((const __attribute__((address_space(1))) u32*)g,
                                     (__attribute__((address_space(3))) u32*)l,
                                     16, 0, 0);
}

// ---------------------------------------------------------------------------
// Fused prep kernel. Grid 1024 x 512 threads, roles by blockIdx PARITY
// (even = lp, odd = xtrans) so both HBM streams overlap under the 2-block/CU
// capacity.
// lp role (b-SPLIT ACROSS WAVES, Wb staged ONCE): waves 0-3 stage each
// 800-float k-chunk into an LDS double buffer (4 k's per phase) via
// global_load_lds; waves 0-3 accumulate b0-7, waves 4-7 accumulate b8-15
// from the SAME staged bytes. Same Wb traffic as R0, 2x waves, half acc
// VGPR. Pacing: m97-style 2-phase with raw s_barrier + counted vmcnt(4)
// (in-flight stages survive the barrier; __syncthreads would drain vmcnt).
// xtrans role: R0-exact 256-thread body, two units per block (tid>>8).
// ---------------------------------------------------------------------------
__global__ __launch_bounds__(512, 4) void prep_kernel(const float* __restrict__ Wb,
                                                      const float* __restrict__ tf,
                                                      const float* __restrict__ x,
                                                      unsigned short* __restrict__ lpF,
                                                      unsigned short* __restrict__ xT) {
    __shared__ __align__(16) char smem[36864];
    int tid = threadIdx.x;

    if ((blockIdx.x & 1) == 0) {
        // ---------------- lp role ----------------
        // lpF[b][tap][kc(4)][wm(2)][mt(4)][lane(64)][j(8)]  (bf16)
        float* cs2         = (float*)smem;                    // [64k][16b] = 4 KB
        char*  ring        = smem + 4096;                     // 2 buf x 4 k x 4 KB
        unsigned short* lt = (unsigned short*)(smem + 4096);  // 25.6 KB, aliases ring

        int chunk = blockIdx.x >> 1;   // 0..511
        int o = chunk >> 2;            // 0..127
        int s = chunk & 3;             // c chunk: c in [32s, 32s+32)

        // coef transposed: cs2[k*16 + b] = mean_t tf[b,t,k] * 0.125
        {
            int idx = tid;
#pragma unroll
            for (int r = 0; r < 2; ++r, idx += 512) {
                int k = idx >> 4, b = idx & 15;
                float sum = 0.f;
#pragma unroll
                for (int t = 0; t < T_; ++t) sum += tf[(b * T_ + t) * K_ + k];
                cs2[idx] = sum * 0.125f;
            }
        }
        __syncthreads();

        // staging geometry: wave w (0..3) stages floats [200w, 200w+200) of
        // each k-chunk into slot offset w*1024 (lanes 50-63 land in the
        // 224 B pad with a clamped in-range source).
        int w_   = (tid >> 6) & 3;
        bool stager = tid < 256;
        int ln_  = tid & 63;
        int cln  = ln_ < 50 ? ln_ : 49;
        const float* wp = Wb + o * 3200 + s * 800 + w_ * 200 + cln * 4;

        // consumer geometry: halves of the block do b 0-7 / b 8-15 on the
        // same staged floats. thread u<200 owns floats [4u,4u+4).
        int u    = tid & 255;
        int half = tid >> 8;
        int myoff = ((u / 50) << 10) + (u % 50) * 16;   // byte off in 4KB slot
        bool cons = u < 200;

        float4 acc[8];
#pragma unroll
        for (int b = 0; b < 8; ++b) acc[b] = make_float4(0.f, 0.f, 0.f, 0.f);

        // prologue: stage k=0..3 into buf 0
        if (stager) {
#pragma unroll
            for (int kk = 0; kk < 4; ++kk)
                stage16(wp + (size_t)kk * WSZ, ring + kk * 4096 + w_ * 1024);
        }

#pragma unroll 2
        for (int g = 0; g < 16; ++g) {
            int buf = g & 1;
            char* curb = ring + buf * 16384;
            char* nxtb = ring + (buf ^ 1) * 16384;
            if (stager) {
                int kn = ((g + 1) * 4) & 63;     // g=15 wraps to k0-3: harmless
#pragma unroll
                for (int kk = 0; kk < 4; ++kk)
                    stage16(wp + (size_t)(kn + kk) * WSZ, nxtb + kk * 4096 + w_ * 1024);
            }
            asm volatile("s_waitcnt vmcnt(4)" ::: "memory");  // cur buf DMA done
            __builtin_amdgcn_s_barrier();                     // raw: no vmcnt drain
            __builtin_amdgcn_sched_barrier(0);                // reads stay below
            if (cons) {
#pragma unroll
                for (int kk = 0; kk < 4; ++kk) {
                    int k = g * 4 + kk;
                    float4 wv = *(const float4*)(curb + kk * 4096 + myoff);
                    const float4* cp = (const float4*)(cs2 + k * 16 + half * 8);
                    float4 c0 = cp[0], c1 = cp[1];
                    acc[0].x += c0.x * wv.x; acc[0].y += c0.x * wv.y;
                    acc[0].z += c0.x * wv.z; acc[0].w += c0.x * wv.w;
                    acc[1].x += c0.y * wv.x; acc[1].y += c0.y * wv.y;
                    acc[1].z += c0.y * wv.z; acc[1].w += c0.y * wv.w;
                    acc[2].x += c0.z * wv.x; acc[2].y += c0.z * wv.y;
                    acc[2].z += c0.z * wv.z; acc[2].w += c0.z * wv.w;
                    acc[3].x += c0.w * wv.x; acc[3].y += c0.w * wv.y;
                    acc[3].z += c0.w * wv.z; acc[3].w += c0.w * wv.w;
                    acc[4].x += c1.x * wv.x; acc[4].y += c1.x * wv.y;
                    acc[4].z += c1.x * wv.z; acc[4].w += c1.x * wv.w;
                    acc[5].x += c1.y * wv.x; acc[5].y += c1.y * wv.y;
                    acc[5].z += c1.y * wv.z; acc[5].w += c1.y * wv.w;
                    acc[6].x += c1.z * wv.x; acc[6].y += c1.z * wv.y;
                    acc[6].z += c1.z * wv.z; acc[6].w += c1.z * wv.w;
                    acc[7].x += c1.w * wv.x; acc[7].y += c1.w * wv.y;
                    acc[7].z += c1.w * wv.z; acc[7].w += c1.w * wv.w;
                }
            }
            asm volatile("s_waitcnt lgkmcnt(0)" ::: "memory"); // reads retired
            __builtin_amdgcn_sched_barrier(0);
            __builtin_amdgcn_s_barrier();                      // buf reusable
        }

        asm volatile("s_waitcnt vmcnt(0)" ::: "memory");  // drain wrap stages
        __syncthreads();                                  // ring dead; lt safe

        if (cons) {
            unsigned int* ltw = (unsigned int*)lt;
#pragma unroll
            for (int lb = 0; lb < 8; ++lb) {
                int b = half * 8 + lb;
                ltw[b * 400 + u * 2]     = pack2(acc[lb].x, acc[lb].y);
                ltw[b * 400 + u * 2 + 1] = pack2(acc[lb].z, acc[lb].w);
            }
        }
        __syncthreads();

        // fragment-ordered writeout (R0-exact, 512-thread stride)
        int wm = o >> 6, mt = (o >> 4) & 3, n16 = o & 15;
        for (int it = tid; it < 1600; it += 512) {
            int b = it / 100;
            int r = it - b * 100;
            int tap = r >> 2;
            int quad = r & 3;
            unsigned short v[8];
#pragma unroll
            for (int j = 0; j < 8; ++j)
                v[j] = lt[b * 800 + (quad * 8 + j) * 25 + tap];
            size_t off = (size_t)b * 409600
                       + (size_t)((((tap * 4 + s) * 2 + wm) * 4 + mt) * 512
                                  + quad * 128 + n16 * 8);
            *(uint4*)(lpF + off) = *(const uint4*)v;
        }
    } else {
        // ---------------- xtrans role (R0-exact body, 2 units/block) ------
        int h2 = tid >> 8;                     // unit half 0/1
        int t2 = tid & 255;
        unsigned short* ls = (unsigned short*)(smem + h2 * 17408);  // 64*136*2
        int q = (blockIdx.x >> 1) * 2 + h2;    // 0..1023
        int b = q >> 6, h = q & 63;

        int w = t2 & 63, cb = t2 >> 6;         // cb: 4 groups of 32 c
        const float* xp = x + (((size_t)(b * CIN + cb * 32) * H_ + h) * W_) + w;
#pragma unroll
        for (int p = 0; p < 16; ++p) {
            float f0 = xp[(size_t)(2 * p) * (H_ * W_)];
            float f1 = xp[(size_t)(2 * p + 1) * (H_ * W_)];
            *(unsigned int*)&ls[w * 136 + cb * 32 + 2 * p] = pack2(f0, f1);
        }
        __syncthreads();

        unsigned short* xTb = xT + ((size_t)(b * 64 + h) * 64) * 128;
        int chunk = t2 & 15, wr = t2 >> 4;
#pragma unroll
        for (int pass = 0; pass < 4; ++pass) {
            int ww = pass * 16 + wr;
            uint4 v = *(const uint4*)&ls[ww * 136 + chunk * 8];
            *(uint4*)&xTb[ww * 128 + chunk * 8] = v;
        }
    }
}

// ---------------------------------------------------------------------------
// Conv as 25 shifted GEMMs, bf16 MFMA 16x16x32, fp32 accum. R5-exact.
// Wave wq owns an o-quarter (32 o) x all 128 pixels; A read once per block.
// Grid: 512 blocks, XCD-swizzled (2 batches per XCD's L2).
// ---------------------------------------------------------------------------
__global__ __launch_bounds__(256) void conv_mfma(const unsigned short* __restrict__ xT,
                                                 const unsigned short* __restrict__ lpF,
                                                 float* __restrict__ out) {
    int bid = blockIdx.x;
    int b  = (bid & 7) | (((bid >> 3) & 1) << 3);   // XCD-local batch
    int h0 = (bid >> 4) << 1;                       // row pair

    int tid  = threadIdx.x;
    int lane = tid & 63, wq = tid >> 6;       // wq: o-quarter 0..3
    int n16 = lane & 15, quad = lane >> 4;

    __shared__ __align__(16) unsigned short xs[408 * 40];   // 32640 B

    f32x4 acc[2][8];
#pragma unroll
    for (int mt = 0; mt < 2; ++mt)
#pragma unroll
        for (int nt = 0; nt < 8; ++nt) acc[mt][nt] = (f32x4){0.f, 0.f, 0.f, 0.f};

    const unsigned short* xTb = xT + (size_t)b * (64 * 64 * 128);
    const unsigned short* lpW = lpF + (size_t)b * 409600
                              + (wq >> 1) * 2048 + (wq & 1) * 1024 + lane * 8;

#define LOAD_FRAGS(A, Bf, tap) do {                                          \
    int i_ = (tap) / 5, j_ = (tap) - 5 * (i_);                               \
    const unsigned short* ap_ = lpW + (tap) * 16384 + kcB;                   \
    A[0] = *(const bf16x8*)(ap_);                                            \
    A[1] = *(const bf16x8*)(ap_ + 512);                                      \
    const unsigned short* bp_ = &xs[((i_) * 68 + n16 + j_) * 40 + quad * 8]; \
    Bf[0] = *(const bf16x8*)(bp_);                                           \
    Bf[1] = *(const bf16x8*)(bp_ + 16 * 40);                                 \
    Bf[2] = *(const bf16x8*)(bp_ + 32 * 40);                                 \
    Bf[3] = *(const bf16x8*)(bp_ + 48 * 40);                                 \
    Bf[4] = *(const bf16x8*)(bp_ + 68 * 40);                                 \
    Bf[5] = *(const bf16x8*)(bp_ + (68 + 16) * 40);                          \
    Bf[6] = *(const bf16x8*)(bp_ + (68 + 32) * 40);                          \
    Bf[7] = *(const bf16x8*)(bp_ + (68 + 48) * 40);                          \
} while (0)

#define DO_MFMA(av, bv) do {                                                 \
    _Pragma("unroll") for (int mt = 0; mt < 2; ++mt)                         \
    _Pragma("unroll") for (int nt = 0; nt < 8; ++nt)                         \
        acc[mt][nt] = __builtin_amdgcn_mfma_f32_16x16x32_bf16(               \
            (av)[mt], (bv)[nt], acc[mt][nt], 0, 0, 0);                       \
} while (0)

    for (int kc = 0; kc < 4; ++kc) {
        int kcOff = kc * 32;
        int kcB   = kc * 4096;
        __syncthreads();                       // previous chunk's readers done
        for (int sIdx = tid; sIdx < 408; sIdx += 256) {
            unsigned int su = (unsigned int)sIdx;
            int rr = su / 68u;
            int ww = su - rr * 68u;
            int gr = h0 - 2 + rr, gw = ww - 2;
            uint4* dst = (uint4*)&xs[sIdx * 40];
            if ((unsigned)gr < 64u && (unsigned)gw < 64u) {
                const uint4* src = (const uint4*)(xTb + (((size_t)gr * 64 + gw) * 128 + kcOff));
                dst[0] = src[0]; dst[1] = src[1]; dst[2] = src[2]; dst[3] = src[3];
            } else {
                uint4 z = {0u, 0u, 0u, 0u};
                dst[0] = z; dst[1] = z; dst[2] = z; dst[3] = z;
            }
        }
        __syncthreads();

        bf16x8 a0[2], b0[8], a1[2], b1[8];
        LOAD_FRAGS(a0, b0, 0);
        for (int t = 0; t < 24; t += 2) {
            LOAD_FRAGS(a1, b1, t + 1);
            DO_MFMA(a0, b0);
            LOAD_FRAGS(a0, b0, t + 2);
            DO_MFMA(a1, b1);
        }
        DO_MFMA(a0, b0);                       // tap 24
    }

    // epilogue: o = wq*32 + mt*16 + quad*4 + r; h = h0+(nt>>2); w = (nt&3)*16+n16
    float* outb = out + (size_t)b * (COUT * H_ * W_);
#pragma unroll
    for (int mt = 0; mt < 2; ++mt) {
#pragma unroll
        for (int nt = 0; nt < 8; ++nt) {
#pragma unroll
            for (int r = 0; r < 4; ++r) {
                int o = wq * 32 + mt * 16 + quad * 4 + r;
                int h = h0 + (nt >> 2);
                int w = (nt & 3) * 16 + n16;
                outb[(size_t)o * (H_ * W_) + (size_t)h * W_ + w] = acc[mt][nt][r];
            }
        }
    }
#undef LOAD_FRAGS
#undef DO_MFMA
}

// ---------------------------------------------------------------------------
extern "C" void kernel_launch(void* const* d_in, const int* in_sizes, int n_in,
                              void* d_out, int out_size, void* d_ws, size_t ws_size,
                              hipStream_t stream) {
    const float* x  = (const float*)d_in[0];   // (16,128,64,64)
    const float* tf = (const float*)d_in[1];   // (16,8,64)
    const float* Wb = (const float*)d_in[2];   // (64,128,128,5,5)
    float* out = (float*)d_out;                // (16,128,64,64) fp32

    // ws: lpF bf16 fragment-ordered 16*409600 = 13.1 MB, then xT bf16 16.8 MB
    unsigned short* lpF = (unsigned short*)d_ws;
    unsigned short* xT  = lpF + (size_t)B_ * 409600;

    prep_kernel<<<1024, 512, 0, stream>>>(Wb, tf, x, lpF, xT);
    conv_mfma  <<<512,  256, 0, stream>>>(xT, lpF, out);
}

// Round 9
// 235.843 us; speedup vs baseline: 1.0788x; 1.0712x over previous
//
#include <hip/hip_runtime.h>

#define B_    16
#define T_    8
#define K_    64
#define COUT  128
#define CIN   128
#define H_    64
#define W_    64
#define WSZ   (COUT*CIN*5*5)        // 409600 per-k (and per-b) weight elems

typedef __bf16 bf16x8 __attribute__((ext_vector_type(8)));
typedef float  f32x4  __attribute__((ext_vector_type(4)));

static __device__ __forceinline__ unsigned short f2bf(float f) {
    unsigned int u = __builtin_bit_cast(unsigned int, f);
    unsigned int r = (u + 0x7FFFu + ((u >> 16) & 1u)) >> 16;
    return (unsigned short)r;
}

static __device__ __forceinline__ unsigned int pack2(float lo, float hi) {
    return (unsigned int)f2bf(lo) | ((unsigned int)f2bf(hi) << 16);
}

// ---------------------------------------------------------------------------
// Fused prep kernel — R0-EXACT (proven 69 us; frozen).
// Grid 1536 blocks: [0,512) lp role, [512,1536) xtrans role.
// ---------------------------------------------------------------------------
__global__ __launch_bounds__(256) void prep_kernel(const float* __restrict__ Wb,
                                                   const float* __restrict__ tf,
                                                   const float* __restrict__ x,
                                                   unsigned short* __restrict__ lpF,
                                                   unsigned short* __restrict__ xT) {
    __shared__ __align__(16) char smem[30720];
    int tid = threadIdx.x;

    if (blockIdx.x < 512) {
        // ---------------- lp role ----------------
        // lpF[b][tap][kc(4)][wm(2)][mt(4)][lane(64)][j(8)]  (bf16)
        //   o = wm*64 + mt*16 + (lane&15), c = kc*32 + (lane>>4)*8 + j
        float* cs          = (float*)smem;                       // 4 KB
        unsigned short* lt = (unsigned short*)(smem + 4096);     // 25.6 KB

        int o = blockIdx.x >> 2;      // 0..127
        int s = blockIdx.x & 3;       // c chunk: c in [32s, 32s+32)

        // coef[b,k] = mean_t tf[b,t,k]
        {
            int idx = tid;
#pragma unroll
            for (int r = 0; r < 4; ++r, idx += 256) {
                int b = idx >> 6, k = idx & 63;
                float sum = 0.f;
#pragma unroll
                for (int t = 0; t < T_; ++t) sum += tf[(b * T_ + t) * K_ + k];
                cs[idx] = sum * 0.125f;
            }
        }
        __syncthreads();

        if (tid < 200) {
            int base = o * 3200 + s * 800 + tid * 4;
            float4 acc[B_];
#pragma unroll
            for (int b = 0; b < B_; ++b) acc[b] = make_float4(0.f, 0.f, 0.f, 0.f);

#pragma unroll 4
            for (int k = 0; k < K_; ++k) {
                const float4 wv = *(const float4*)(Wb + (size_t)k * WSZ + base);
#pragma unroll
                for (int b = 0; b < B_; ++b) {
                    float c = cs[b * K_ + k];
                    acc[b].x += c * wv.x;
                    acc[b].y += c * wv.y;
                    acc[b].z += c * wv.z;
                    acc[b].w += c * wv.w;
                }
            }
            unsigned int* ltw = (unsigned int*)lt;
#pragma unroll
            for (int b = 0; b < B_; ++b) {
                ltw[b * 400 + tid * 2]     = pack2(acc[b].x, acc[b].y);
                ltw[b * 400 + tid * 2 + 1] = pack2(acc[b].z, acc[b].w);
            }
        }
        __syncthreads();

        // fragment-ordered writeout: wm,mt,n16 fixed per block; quad varies
        int wm = o >> 6, mt = (o >> 4) & 3, n16 = o & 15;
        for (int it = tid; it < 1600; it += 256) {
            int b = it / 100;
            int r = it - b * 100;
            int tap = r >> 2;
            int quad = r & 3;
            unsigned short v[8];
#pragma unroll
            for (int j = 0; j < 8; ++j)
                v[j] = lt[b * 800 + (quad * 8 + j) * 25 + tap];
            size_t off = (size_t)b * 409600
                       + (size_t)((((tap * 4 + s) * 2 + wm) * 4 + mt) * 512
                                  + quad * 128 + n16 * 8);
            *(uint4*)(lpF + off) = *(const uint4*)v;
        }
    } else {
        // ---------------- xtrans role ----------------
        unsigned short* ls = (unsigned short*)smem;              // 64*136*2 = 17.4 KB
        int q = blockIdx.x - 512;
        int b = q >> 6, h = q & 63;

        int w = tid & 63, cb = tid >> 6;          // cb: 4 groups of 32 c
        const float* xp = x + (((size_t)(b * CIN + cb * 32) * H_ + h) * W_) + w;
#pragma unroll
        for (int p = 0; p < 16; ++p) {
            float f0 = xp[(size_t)(2 * p) * (H_ * W_)];
            float f1 = xp[(size_t)(2 * p + 1) * (H_ * W_)];
            *(unsigned int*)&ls[w * 136 + cb * 32 + 2 * p] = pack2(f0, f1);
        }
        __syncthreads();

        unsigned short* xTb = xT + ((size_t)(b * 64 + h) * 64) * 128;
        int chunk = tid & 15, wr = tid >> 4;
#pragma unroll
        for (int pass = 0; pass < 4; ++pass) {
            int ww = pass * 16 + wr;
            uint4 v = *(const uint4*)&ls[ww * 136 + chunk * 8];
            *(uint4*)&xTb[ww * 128 + chunk * 8] = v;
        }
    }
}

// ---------------------------------------------------------------------------
// Conv as 25 shifted GEMMs, bf16 MFMA 16x16x32, fp32 accum.
// CHANGE vs R5: tap order j-OUTER / i-INNER with a 3-row rolling register
// window. Taps (i,j) and (i+1,j) share xs row i+1 (4 of 8 B-frags); rolling
// keeps each row's 4 fragments in registers for both of its consumer taps:
// B ds_read_b128 per wave per kc drops 200 -> 120 (6 rows x 4 frags x 5 j).
// The 3-deep window (R0/R1/R2) makes each iteration's loads feed the NEXT
// iteration's MFMAs (full latency overlap, all static indices).
// Wave wq owns o-quarter (32 o) x 128 px; A read once per block (R5 map).
// Staging, barriers, acc mapping, epilogue: R5-exact.
// ---------------------------------------------------------------------------
__global__ __launch_bounds__(256) void conv_mfma(const unsigned short* __restrict__ xT,
                                                 const unsigned short* __restrict__ lpF,
                                                 float* __restrict__ out) {
    int bid = blockIdx.x;
    int b  = (bid & 7) | (((bid >> 3) & 1) << 3);   // XCD-local batch
    int h0 = (bid >> 4) << 1;                       // row pair

    int tid  = threadIdx.x;
    int lane = tid & 63, wq = tid >> 6;       // wq: o-quarter 0..3
    int n16 = lane & 15, quad = lane >> 4;

    __shared__ __align__(16) unsigned short xs[408 * 40];   // 32640 B

    f32x4 acc[2][8];
#pragma unroll
    for (int mt = 0; mt < 2; ++mt)
#pragma unroll
        for (int nt = 0; nt < 8; ++nt) acc[mt][nt] = (f32x4){0.f, 0.f, 0.f, 0.f};

    const unsigned short* xTb = xT + (size_t)b * (64 * 64 * 128);
    const unsigned short* lpW = lpF + (size_t)b * 409600
                              + (wq >> 1) * 2048 + (wq & 1) * 1024 + lane * 8;

    for (int kc = 0; kc < 4; ++kc) {
        int kcOff = kc * 32;
        int kcB   = kc * 4096;
        __syncthreads();                       // previous chunk's readers done
        // stage x rows h0-2 .. h0+3, cols -2..65 (zeros outside), 32 channels
        for (int sIdx = tid; sIdx < 408; sIdx += 256) {
            unsigned int su = (unsigned int)sIdx;
            int rr = su / 68u;
            int ww = su - rr * 68u;
            int gr = h0 - 2 + rr, gw = ww - 2;
            uint4* dst = (uint4*)&xs[sIdx * 40];
            if ((unsigned)gr < 64u && (unsigned)gw < 64u) {
                const uint4* src = (const uint4*)(xTb + (((size_t)gr * 64 + gw) * 128 + kcOff));
                dst[0] = src[0]; dst[1] = src[1]; dst[2] = src[2]; dst[3] = src[3];
            } else {
                uint4 z = {0u, 0u, 0u, 0u};
                dst[0] = z; dst[1] = z; dst[2] = z; dst[3] = z;
            }
        }
        __syncthreads();

#pragma unroll
        for (int j = 0; j < 5; ++j) {
            // row r's 4 fragments (nt px-blocks): rp + r*2720 + nt*640
            const unsigned short* rp = &xs[(n16 + j) * 40 + quad * 8];

            bf16x8 R0[4], R1[4], R2[4];       // rolling rows i, i+1, i+2
            bf16x8 A0[2], A1[2];
#pragma unroll
            for (int nt = 0; nt < 4; ++nt) R0[nt] = *(const bf16x8*)(rp + nt * 640);
#pragma unroll
            for (int nt = 0; nt < 4; ++nt) R1[nt] = *(const bf16x8*)(rp + 2720 + nt * 640);
            {
                const unsigned short* ap = lpW + j * 16384 + kcB;   // tap (0,j)
                A0[0] = *(const bf16x8*)(ap);
                A0[1] = *(const bf16x8*)(ap + 512);
            }
#pragma unroll
            for (int i = 0; i < 5; ++i) {
                if (i < 4) {
                    const unsigned short* rpn = rp + (i + 2) * 2720;
#pragma unroll
                    for (int nt = 0; nt < 4; ++nt)
                        R2[nt] = *(const bf16x8*)(rpn + nt * 640);
                    const unsigned short* apn = lpW + ((i + 1) * 5 + j) * 16384 + kcB;
                    A1[0] = *(const bf16x8*)(apn);
                    A1[1] = *(const bf16x8*)(apn + 512);
                }
                // acc[mt][nt]   += A0[mt] x R0[nt]   (output row h0)
                // acc[mt][nt+4] += A0[mt] x R1[nt]   (output row h0+1)
#pragma unroll
                for (int mt = 0; mt < 2; ++mt)
#pragma unroll
                    for (int nt = 0; nt < 4; ++nt) {
                        acc[mt][nt] = __builtin_amdgcn_mfma_f32_16x16x32_bf16(
                            A0[mt], R0[nt], acc[mt][nt], 0, 0, 0);
                        acc[mt][nt + 4] = __builtin_amdgcn_mfma_f32_16x16x32_bf16(
                            A0[mt], R1[nt], acc[mt][nt + 4], 0, 0, 0);
                    }
                // rotate window (static, unrolled -> register renaming)
#pragma unroll
                for (int nt = 0; nt < 4; ++nt) { R0[nt] = R1[nt]; R1[nt] = R2[nt]; }
                A0[0] = A1[0]; A0[1] = A1[1];
            }
        }
    }

    // epilogue: o = wq*32 + mt*16 + quad*4 + r; h = h0+(nt>>2); w = (nt&3)*16+n16
    float* outb = out + (size_t)b * (COUT * H_ * W_);
#pragma unroll
    for (int mt = 0; mt < 2; ++mt) {
#pragma unroll
        for (int nt = 0; nt < 8; ++nt) {
#pragma unroll
            for (int r = 0; r < 4; ++r) {
                int o = wq * 32 + mt * 16 + quad * 4 + r;
                int h = h0 + (nt >> 2);
                int w = (nt & 3) * 16 + n16;
                outb[(size_t)o * (H_ * W_) + (size_t)h * W_ + w] = acc[mt][nt][r];
            }
        }
    }
}

// ---------------------------------------------------------------------------
extern "C" void kernel_launch(void* const* d_in, const int* in_sizes, int n_in,
                              void* d_out, int out_size, void* d_ws, size_t ws_size,
                              hipStream_t stream) {
    const float* x  = (const float*)d_in[0];   // (16,128,64,64)
    const float* tf = (const float*)d_in[1];   // (16,8,64)
    const float* Wb = (const float*)d_in[2];   // (64,128,128,5,5)
    float* out = (float*)d_out;                // (16,128,64,64) fp32

    // ws: lpF bf16 fragment-ordered 16*409600 = 13.1 MB, then xT bf16 16.8 MB
    unsigned short* lpF = (unsigned short*)d_ws;
    unsigned short* xT  = lpF + (size_t)B_ * 409600;

    prep_kernel<<<1536, 256, 0, stream>>>(Wb, tf, x, lpF, xT);
    conv_mfma  <<<512,  256, 0, stream>>>(xT, lpF, out);
}